// Round 15
// baseline (877.409 us; speedup 1.0000x reference)
//
#include <hip/hip_runtime.h>

#define NSEQ 2048
#define DMODEL 1024
#define NHEAD 16
#define HDIM 64
#define NBATCH 4
#define MTOT 8192
#define ATT_SCALE 0.125f
#define LOG2E 1.4426950408889634f
#define SM_SHIFT 12.0f

typedef __bf16 bf16x8 __attribute__((ext_vector_type(8)));
typedef float f32x4 __attribute__((ext_vector_type(4)));
typedef unsigned int u32x4 __attribute__((ext_vector_type(4)));
typedef unsigned short u16;
typedef unsigned int u32;
typedef unsigned long long u64;

__device__ __forceinline__ u16 f2bf(float f) {
  u32 u = __builtin_bit_cast(u32, f);
  return (u16)((u + 0x7fffu + ((u >> 16) & 1u)) >> 16);
}

__device__ __forceinline__ void gload_lds16(const void* g, void* l) {
  __builtin_amdgcn_global_load_lds(
      (__attribute__((address_space(1))) const u32*)g,
      (__attribute__((address_space(3))) u32*)l, 16, 0, 0);
}

// ---------------- cast fp32 -> bf16 (x) ----------------
__global__ __launch_bounds__(256) void cast_f32_bf16(const float* __restrict__ in,
                                                     u16* __restrict__ out, int n) {
  int i = (blockIdx.x * 256 + threadIdx.x) * 4;
  if (i >= n) return;
  float4 v = *(const float4*)(in + i);
  ushort4 o;
  o.x = f2bf(v.x); o.y = f2bf(v.y); o.z = f2bf(v.z); o.w = f2bf(v.w);
  *(ushort4*)(out + i) = o;
}

// ---------------- cast 4 weights -> contiguous bf16 block ----------------
__global__ __launch_bounds__(256) void cast_w4(const float* __restrict__ a,
                                               const float* __restrict__ b,
                                               const float* __restrict__ c,
                                               const float* __restrict__ d,
                                               u16* __restrict__ out) {
  int bid = blockIdx.x;
  int which = bid >> 10, lb = bid & 1023;
  const float* src = (which == 0) ? a : (which == 1) ? b : (which == 2) ? c : d;
  int i = (lb * 256 + threadIdx.x) * 4;
  float4 v = *(const float4*)(src + i);
  ushort4 o;
  o.x = f2bf(v.x); o.y = f2bf(v.y); o.z = f2bf(v.z); o.w = f2bf(v.w);
  *(ushort4*)(out + (size_t)which * 1048576 + i) = o;
}

// ---------------- pack mask int32 -> bit per element ----------------
__global__ __launch_bounds__(256) void pack_mask(const int* __restrict__ mask,
                                                 u64* __restrict__ bits) {
  int wave = (blockIdx.x * 256 + threadIdx.x) >> 6;
  int lane = threadIdx.x & 63;
  const int* row = mask + (size_t)wave * NSEQ;
  u64* out = bits + (size_t)wave * 32;
  for (int c = 0; c < 32; ++c) {
    int v = row[c * 64 + lane];
    u64 bl = __ballot(v != 0);
    if (lane == 0) out[c] = bl;
  }
}

// ---------------- fused QKV GEMM: C[m,n] = sum_k A[m,k]*Wc[n,k], N=3072 ----------------
// bn 0..7 -> Q [B,H,N,64]; 8..15 -> K [B,H,N,64]; 16..23 -> V^T [B,H,64,NSEQ]
__global__ __launch_bounds__(256) void gemm_qkv(const u16* __restrict__ A,
                                                const u16* __restrict__ Wc,
                                                u16* __restrict__ qo,
                                                u16* __restrict__ ko,
                                                u16* __restrict__ vo) {
  __shared__ __align__(16) u16 Al[128 * 64];
  __shared__ __align__(16) u16 Bl[128 * 64];
  const int tid = threadIdx.x;
  const int w = tid >> 6, l = tid & 63;
  const int l15 = l & 15, l4 = l >> 4;
  const int bm = blockIdx.x, bn = blockIdx.y;
  const int wm = w >> 1, wn = w & 1;

  f32x4 acc[4][4] = {};

  for (int ks = 0; ks < 1024; ks += 64) {
    __syncthreads();
#pragma unroll
    for (int c = 0; c < 4; ++c) {
      int g = w * 256 + c * 64 + l;
      int row = g >> 3, gc = g & 7;
      int sgc = gc ^ (row & 7);
      gload_lds16(A + (size_t)(bm * 128 + row) * 1024 + ks + sgc * 8, &Al[g * 8]);
      gload_lds16(Wc + (size_t)(bn * 128 + row) * 1024 + ks + sgc * 8, &Bl[g * 8]);
    }
    __syncthreads();
#pragma unroll
    for (int kc = 0; kc < 2; ++kc) {
      bf16x8 af[4], bfr[4];
#pragma unroll
      for (int mi = 0; mi < 4; ++mi) {
        int row = wm * 64 + mi * 16 + l15;
        int gc2 = (kc * 4 + l4) ^ (row & 7);
        af[mi] = *(const bf16x8*)&Al[row * 64 + gc2 * 8];
      }
#pragma unroll
      for (int ni = 0; ni < 4; ++ni) {
        int row = wn * 64 + ni * 16 + l15;
        int gc2 = (kc * 4 + l4) ^ (row & 7);
        bfr[ni] = *(const bf16x8*)&Bl[row * 64 + gc2 * 8];
      }
#pragma unroll
      for (int mi = 0; mi < 4; ++mi)
#pragma unroll
        for (int ni = 0; ni < 4; ++ni)
          acc[mi][ni] = __builtin_amdgcn_mfma_f32_16x16x32_bf16(af[mi], bfr[ni],
                                                                acc[mi][ni], 0, 0, 0);
    }
  }

  const int which = bn >> 3;
#pragma unroll
  for (int mi = 0; mi < 4; ++mi)
#pragma unroll
    for (int ni = 0; ni < 4; ++ni)
#pragma unroll
      for (int r = 0; r < 4; ++r) {
        int m = bm * 128 + wm * 64 + mi * 16 + l4 * 4 + r;
        int n = (bn & 7) * 128 + wn * 64 + ni * 16 + l15;
        int b = m >> 11, row = m & 2047, h = n >> 6, d = n & 63;
        u16 val = f2bf(acc[mi][ni][r]);
        size_t bh = (size_t)(b * 16 + h);
        if (which == 0)      qo[(bh * NSEQ + row) * 64 + d] = val;
        else if (which == 1) ko[(bh * NSEQ + row) * 64 + d] = val;
        else                 vo[(bh * 64 + d) * NSEQ + row] = val;
      }
}

// ---------------- final GEMM: out[m,n] = sum_k A[m,k]*W[n,k], fp32 out ----------------
__global__ __launch_bounds__(256) void gemm_out(const u16* __restrict__ A,
                                                const u16* __restrict__ W,
                                                float* __restrict__ C) {
  __shared__ __align__(16) u16 Al[128 * 64];
  __shared__ __align__(16) u16 Bl[128 * 64];
  const int tid = threadIdx.x;
  const int w = tid >> 6, l = tid & 63;
  const int l15 = l & 15, l4 = l >> 4;
  const int bm = blockIdx.x, bn = blockIdx.y;
  const int wm = w >> 1, wn = w & 1;

  f32x4 acc[4][4] = {};

  for (int ks = 0; ks < 1024; ks += 64) {
    __syncthreads();
#pragma unroll
    for (int c = 0; c < 4; ++c) {
      int g = w * 256 + c * 64 + l;
      int row = g >> 3, gc = g & 7;
      int sgc = gc ^ (row & 7);
      gload_lds16(A + (size_t)(bm * 128 + row) * 1024 + ks + sgc * 8, &Al[g * 8]);
      gload_lds16(W + (size_t)(bn * 128 + row) * 1024 + ks + sgc * 8, &Bl[g * 8]);
    }
    __syncthreads();
#pragma unroll
    for (int kc = 0; kc < 2; ++kc) {
      bf16x8 af[4], bfr[4];
#pragma unroll
      for (int mi = 0; mi < 4; ++mi) {
        int row = wm * 64 + mi * 16 + l15;
        int gc2 = (kc * 4 + l4) ^ (row & 7);
        af[mi] = *(const bf16x8*)&Al[row * 64 + gc2 * 8];
      }
#pragma unroll
      for (int ni = 0; ni < 4; ++ni) {
        int row = wn * 64 + ni * 16 + l15;
        int gc2 = (kc * 4 + l4) ^ (row & 7);
        bfr[ni] = *(const bf16x8*)&Bl[row * 64 + gc2 * 8];
      }
#pragma unroll
      for (int mi = 0; mi < 4; ++mi)
#pragma unroll
        for (int ni = 0; ni < 4; ++ni)
          acc[mi][ni] = __builtin_amdgcn_mfma_f32_16x16x32_bf16(af[mi], bfr[ni],
                                                                acc[mi][ni], 0, 0, 0);
    }
  }

#pragma unroll
  for (int mi = 0; mi < 4; ++mi)
#pragma unroll
    for (int ni = 0; ni < 4; ++ni)
#pragma unroll
      for (int r = 0; r < 4; ++r) {
        int m = bm * 128 + wm * 64 + mi * 16 + l4 * 4 + r;
        int n = bn * 128 + wn * 64 + ni * 16 + l15;
        C[(size_t)m * 1024 + n] = acc[mi][ni][r];
      }
}

// ---------------- flash attention (r10 structure, 2 q-groups per wave) ----------------
// 256 thr = 4 waves, grid 1024; each wave handles TWO 16-row q-groups
// (block covers 128 q-rows) -> 36 MFMA per body vs 18, same staging/barrier
// cost, 2x K/V reuse. Both groups processed fully INSIDE the body (nothing
// new lives across the barrier -> no spill mechanism; sync structure
// byte-identical to r10 -> no race mechanism). Fixed-shift softmax + MFMA
// ones-trick row-sum; K staged row-permuted (PV A-slots standard); V as
// contiguous b128; batch-innermost XCD decode.
__global__ __launch_bounds__(256, 4) void attn_kernel(
    const u16* __restrict__ q, const u16* __restrict__ k, const u16* __restrict__ vT,
    const float* __restrict__ alibi, const u64* __restrict__ mbits,
    u16* __restrict__ o) {
  __shared__ __align__(16) u16 Kl[2][64 * 64];
  __shared__ __align__(16) u16 Vl[2][64 * 64];

  const int tid = threadIdx.x, w = tid >> 6, l = tid & 63;
  const int l15 = l & 15, l4 = l >> 4;
  const int W = blockIdx.x;
  // 1024 = 8 XCD * 128; batch innermost for alibi L2 reuse
  const int W2 = (W & 7) * 128 + (W >> 3);
  const int b = W2 & 3, hq = W2 >> 2;
  const int qb = hq & 15, h = hq >> 4;
  const int bh = b * 16 + h;
  const int wq0 = qb * 128 + w * 16;      // group0 rows [wq0, wq0+16)
  const int myq0 = wq0 + l15;             // group1 rows [wq0+64, wq0+80)
  const int myq1 = wq0 + 64 + l15;

  // Q fragments for both groups (B-operand: col q = l15)
  bf16x8 aq0, aq1, aq2, aq3;
  {
    const u16* qrow0 = q + ((size_t)bh * NSEQ + myq0) * 64;
    aq0 = *(const bf16x8*)(qrow0 + l4 * 8);
    aq1 = *(const bf16x8*)(qrow0 + 32 + l4 * 8);
    const u16* qrow1 = q + ((size_t)bh * NSEQ + myq1) * 64;
    aq2 = *(const bf16x8*)(qrow1 + l4 * 8);
    aq3 = *(const bf16x8*)(qrow1 + 32 + l4 * 8);
  }

  // staging pointers. K rows permuted: LDS row p holds global row
  // 32*(p>>5) + 8*((p>>2)&3) + 4*((p>>4)&1) + (p&3)
  const u16* kg[2]; const u16* vg[2];
#pragma unroll
  for (int c = 0; c < 2; ++c) {
    int g = w * 128 + c * 64 + l;
    int row = g >> 3, gc = g & 7, sgc = gc ^ (row & 7);
    int srow = (row & 0x23) | (((row >> 2) & 3) << 3) | (((row >> 4) & 1) << 2);
    kg[c] = k + ((size_t)bh * NSEQ + srow) * 64 + sgc * 8;
    vg[c] = vT + ((size_t)bh * 64 + row) * NSEQ + sgc * 8;
  }

  // per-lane alibi / mask pointers for both q-groups
  const float* alp0 = alibi + (size_t)h * NSEQ * NSEQ + (size_t)myq0 * NSEQ + 8 * l4;
  const float* alp1 = alibi + (size_t)h * NSEQ * NSEQ + (size_t)myq1 * NSEQ + 8 * l4;
  const u64* mrp0 = mbits + ((size_t)b * NSEQ + myq0) * 32;
  const u64* mrp1 = mbits + ((size_t)b * NSEQ + myq1) * 32;

  // LDS read offsets (K and V identical pattern, conflict-free b128)
  const int kfr[2] = { l15 * 128 + (((0 + l4) ^ (l15 & 7)) << 4),
                       l15 * 128 + (((4 + l4) ^ (l15 & 7)) << 4) };

  const u32x4 onesu = {0x3F803F80u, 0x3F803F80u, 0x3F803F80u, 0x3F803F80u};
  const bf16x8 bones = __builtin_bit_cast(bf16x8, onesu);

  f32x4 oaccA[4] = {};  // group0: q = wq0 + l4*4 + r, d = db*16 + l15
  f32x4 oaccB[4] = {};  // group1: q = wq0 + 64 + l4*4 + r
  f32x4 osumA = {}, osumB = {};

  auto stage = [&](u16* KB, u16* VB) {
#pragma unroll
    for (int c = 0; c < 2; ++c) {
      gload_lds16(kg[c], (char*)KB + (w * 128 + c * 64 + l) * 16);
      kg[c] += 4096;
      gload_lds16(vg[c], (char*)VB + (w * 128 + c * 64 + l) * 16);
      vg[c] += 64;
    }
  };

  stage(Kl[0], Vl[0]);
  __syncthreads();

  auto body = [&](const u16* KB, const u16* VB, u16* KN, u16* VN, int t, bool dost) {
    // issue BOTH groups' bias/mask loads up front (group1's gets extra cover)
    float4 a00 = *(const float4*)(alp0 + t * 64);
    float4 a01 = *(const float4*)(alp0 + t * 64 + 4);
    float4 a02 = *(const float4*)(alp0 + t * 64 + 32);
    float4 a03 = *(const float4*)(alp0 + t * 64 + 36);
    u64 mb0 = mrp0[t];
    float4 a10 = *(const float4*)(alp1 + t * 64);
    float4 a11 = *(const float4*)(alp1 + t * 64 + 4);
    float4 a12 = *(const float4*)(alp1 + t * 64 + 32);
    float4 a13 = *(const float4*)(alp1 + t * 64 + 36);
    u64 mb1 = mrp1[t];
    if (dost) stage(KN, VN);

    // K fragments (shared by both groups)
    bf16x8 bk0 = *(const bf16x8*)((const char*)KB + kfr[0]);
    bf16x8 bk1 = *(const bf16x8*)((const char*)KB + kfr[1]);
    bf16x8 bk2 = *(const bf16x8*)((const char*)KB + kfr[0] + 2048);
    bf16x8 bk3 = *(const bf16x8*)((const char*)KB + kfr[1] + 2048);
    bf16x8 bk4 = *(const bf16x8*)((const char*)KB + kfr[0] + 4096);
    bf16x8 bk5 = *(const bf16x8*)((const char*)KB + kfr[1] + 4096);
    bf16x8 bk6 = *(const bf16x8*)((const char*)KB + kfr[0] + 6144);
    bf16x8 bk7 = *(const bf16x8*)((const char*)KB + kfr[1] + 6144);
    // V fragments (shared by both groups)
    bf16x8 bv00 = *(const bf16x8*)((const char*)VB + kfr[0]);
    bf16x8 bv01 = *(const bf16x8*)((const char*)VB + kfr[0] + 2048);
    bf16x8 bv02 = *(const bf16x8*)((const char*)VB + kfr[0] + 4096);
    bf16x8 bv03 = *(const bf16x8*)((const char*)VB + kfr[0] + 6144);
    bf16x8 bv10 = *(const bf16x8*)((const char*)VB + kfr[1]);
    bf16x8 bv11 = *(const bf16x8*)((const char*)VB + kfr[1] + 2048);
    bf16x8 bv12 = *(const bf16x8*)((const char*)VB + kfr[1] + 4096);
    bf16x8 bv13 = *(const bf16x8*)((const char*)VB + kfr[1] + 6144);

#define GROUP(AQ0, AQ1, A0, A1, A2, A3, MB, OSUM, OACC)                        \
    {                                                                          \
      f32x4 z = {0.f, 0.f, 0.f, 0.f};                                          \
      f32x4 st0 = z, st1 = z, st2 = z, st3 = z;                                \
      st0 = __builtin_amdgcn_mfma_f32_16x16x32_bf16(bk0, AQ0, st0, 0, 0, 0);   \
      st0 = __builtin_amdgcn_mfma_f32_16x16x32_bf16(bk1, AQ1, st0, 0, 0, 0);   \
      st1 = __builtin_amdgcn_mfma_f32_16x16x32_bf16(bk2, AQ0, st1, 0, 0, 0);   \
      st1 = __builtin_amdgcn_mfma_f32_16x16x32_bf16(bk3, AQ1, st1, 0, 0, 0);   \
      st2 = __builtin_amdgcn_mfma_f32_16x16x32_bf16(bk4, AQ0, st2, 0, 0, 0);   \
      st2 = __builtin_amdgcn_mfma_f32_16x16x32_bf16(bk5, AQ1, st2, 0, 0, 0);   \
      st3 = __builtin_amdgcn_mfma_f32_16x16x32_bf16(bk6, AQ0, st3, 0, 0, 0);   \
      st3 = __builtin_amdgcn_mfma_f32_16x16x32_bf16(bk7, AQ1, st3, 0, 0, 0);   \
      st0[0] = fmaf(st0[0], ATT_SCALE, A0.x);                                  \
      st0[1] = fmaf(st0[1], ATT_SCALE, A0.y);                                  \
      st0[2] = fmaf(st0[2], ATT_SCALE, A0.z);                                  \
      st0[3] = fmaf(st0[3], ATT_SCALE, A0.w);                                  \
      st1[0] = fmaf(st1[0], ATT_SCALE, A1.x);                                  \
      st1[1] = fmaf(st1[1], ATT_SCALE, A1.y);                                  \
      st1[2] = fmaf(st1[2], ATT_SCALE, A1.z);                                  \
      st1[3] = fmaf(st1[3], ATT_SCALE, A1.w);                                  \
      st2[0] = fmaf(st2[0], ATT_SCALE, A2.x);                                  \
      st2[1] = fmaf(st2[1], ATT_SCALE, A2.y);                                  \
      st2[2] = fmaf(st2[2], ATT_SCALE, A2.z);                                  \
      st2[3] = fmaf(st2[3], ATT_SCALE, A2.w);                                  \
      st3[0] = fmaf(st3[0], ATT_SCALE, A3.x);                                  \
      st3[1] = fmaf(st3[1], ATT_SCALE, A3.y);                                  \
      st3[2] = fmaf(st3[2], ATT_SCALE, A3.z);                                  \
      st3[3] = fmaf(st3[3], ATT_SCALE, A3.w);                                  \
      if (!__all((MB) == ~0ull)) {                                             \
        _Pragma("unroll")                                                      \
        for (int r = 0; r < 4; ++r) {                                          \
          if (!(((MB) >> (8 * l4 + r)) & 1))      st0[r] = -3.0e38f;           \
          if (!(((MB) >> (8 * l4 + 4 + r)) & 1))  st1[r] = -3.0e38f;           \
          if (!(((MB) >> (32 + 8 * l4 + r)) & 1)) st2[r] = -3.0e38f;           \
          if (!(((MB) >> (36 + 8 * l4 + r)) & 1)) st3[r] = -3.0e38f;           \
        }                                                                      \
      }                                                                        \
      float p0 = exp2f(fmaf(st0[0], LOG2E, -SM_SHIFT * LOG2E));                \
      float p1 = exp2f(fmaf(st0[1], LOG2E, -SM_SHIFT * LOG2E));                \
      float p2 = exp2f(fmaf(st0[2], LOG2E, -SM_SHIFT * LOG2E));                \
      float p3 = exp2f(fmaf(st0[3], LOG2E, -SM_SHIFT * LOG2E));                \
      float p4 = exp2f(fmaf(st1[0], LOG2E, -SM_SHIFT * LOG2E));                \
      float p5 = exp2f(fmaf(st1[1], LOG2E, -SM_SHIFT * LOG2E));                \
      float p6 = exp2f(fmaf(st1[2], LOG2E, -SM_SHIFT * LOG2E));                \
      float p7 = exp2f(fmaf(st1[3], LOG2E, -SM_SHIFT * LOG2E));                \
      float p8 = exp2f(fmaf(st2[0], LOG2E, -SM_SHIFT * LOG2E));                \
      float p9 = exp2f(fmaf(st2[1], LOG2E, -SM_SHIFT * LOG2E));                \
      float pA = exp2f(fmaf(st2[2], LOG2E, -SM_SHIFT * LOG2E));                \
      float pB = exp2f(fmaf(st2[3], LOG2E, -SM_SHIFT * LOG2E));                \
      float pC = exp2f(fmaf(st3[0], LOG2E, -SM_SHIFT * LOG2E));                \
      float pD = exp2f(fmaf(st3[1], LOG2E, -SM_SHIFT * LOG2E));                \
      float pE = exp2f(fmaf(st3[2], LOG2E, -SM_SHIFT * LOG2E));                \
      float pF = exp2f(fmaf(st3[3], LOG2E, -SM_SHIFT * LOG2E));                \
      u32 W0, W1, W2_, W3, W4, W5, W6, W7;                                     \
      asm("v_cvt_pk_bf16_f32 %0, %1, %2" : "=v"(W0) : "v"(p0), "v"(p1));       \
      asm("v_cvt_pk_bf16_f32 %0, %1, %2" : "=v"(W1) : "v"(p2), "v"(p3));       \
      asm("v_cvt_pk_bf16_f32 %0, %1, %2" : "=v"(W2_) : "v"(p4), "v"(p5));      \
      asm("v_cvt_pk_bf16_f32 %0, %1, %2" : "=v"(W3) : "v"(p6), "v"(p7));       \
      asm("v_cvt_pk_bf16_f32 %0, %1, %2" : "=v"(W4) : "v"(p8), "v"(p9));       \
      asm("v_cvt_pk_bf16_f32 %0, %1, %2" : "=v"(W5) : "v"(pA), "v"(pB));       \
      asm("v_cvt_pk_bf16_f32 %0, %1, %2" : "=v"(W6) : "v"(pC), "v"(pD));       \
      asm("v_cvt_pk_bf16_f32 %0, %1, %2" : "=v"(W7) : "v"(pE), "v"(pF));       \
      u32x4 wv0 = {W0, W1, W2_, W3};                                           \
      bf16x8 pa = __builtin_bit_cast(bf16x8, wv0);                             \
      OSUM = __builtin_amdgcn_mfma_f32_16x16x32_bf16(pa, bones, OSUM, 0, 0, 0);\
      OACC[0] = __builtin_amdgcn_mfma_f32_16x16x32_bf16(pa, bv00, OACC[0], 0, 0, 0); \
      OACC[1] = __builtin_amdgcn_mfma_f32_16x16x32_bf16(pa, bv01, OACC[1], 0, 0, 0); \
      OACC[2] = __builtin_amdgcn_mfma_f32_16x16x32_bf16(pa, bv02, OACC[2], 0, 0, 0); \
      OACC[3] = __builtin_amdgcn_mfma_f32_16x16x32_bf16(pa, bv03, OACC[3], 0, 0, 0); \
      u32x4 wv1 = {W4, W5, W6, W7};                                            \
      pa = __builtin_bit_cast(bf16x8, wv1);                                    \
      OSUM = __builtin_amdgcn_mfma_f32_16x16x32_bf16(pa, bones, OSUM, 0, 0, 0);\
      OACC[0] = __builtin_amdgcn_mfma_f32_16x16x32_bf16(pa, bv10, OACC[0], 0, 0, 0); \
      OACC[1] = __builtin_amdgcn_mfma_f32_16x16x32_bf16(pa, bv11, OACC[1], 0, 0, 0); \
      OACC[2] = __builtin_amdgcn_mfma_f32_16x16x32_bf16(pa, bv12, OACC[2], 0, 0, 0); \
      OACC[3] = __builtin_amdgcn_mfma_f32_16x16x32_bf16(pa, bv13, OACC[3], 0, 0, 0); \
    }

    GROUP(aq0, aq1, a00, a01, a02, a03, mb0, osumA, oaccA)
    GROUP(aq2, aq3, a10, a11, a12, a13, mb1, osumB, oaccB)
#undef GROUP
    __syncthreads();
  };

  for (int t2 = 0; t2 < 16; ++t2) {
    body(Kl[0], Vl[0], Kl[1], Vl[1], t2 * 2, true);
    body(Kl[1], Vl[1], Kl[0], Vl[0], t2 * 2 + 1, t2 < 15);
  }

  // normalize + write O for both groups; shfl-free
#pragma unroll
  for (int r = 0; r < 4; ++r) {
    float invA = __builtin_amdgcn_rcpf(osumA[r]);
    int qq = wq0 + l4 * 4 + r;
    u16* orow = o + ((size_t)b * NSEQ + qq) * DMODEL + h * 64 + l15;
    orow[0]  = f2bf(oaccA[0][r] * invA);
    orow[16] = f2bf(oaccA[1][r] * invA);
    orow[32] = f2bf(oaccA[2][r] * invA);
    orow[48] = f2bf(oaccA[3][r] * invA);
    float invB = __builtin_amdgcn_rcpf(osumB[r]);
    u16* orow2 = o + ((size_t)b * NSEQ + qq + 64) * DMODEL + h * 64 + l15;
    orow2[0]  = f2bf(oaccB[0][r] * invB);
    orow2[16] = f2bf(oaccB[1][r] * invB);
    orow2[32] = f2bf(oaccB[2][r] * invB);
    orow2[48] = f2bf(oaccB[3][r] * invB);
  }
}

extern "C" void kernel_launch(void* const* d_in, const int* in_sizes, int n_in,
                              void* d_out, int out_size, void* d_ws, size_t ws_size,
                              hipStream_t stream) {
  (void)in_sizes; (void)n_in; (void)out_size; (void)ws_size;
  const float* x = (const float*)d_in[0];
  const int* mask = (const int*)d_in[1];
  const float* alibi = (const float*)d_in[2];
  const float* Wq = (const float*)d_in[3];
  const float* Wk = (const float*)d_in[4];
  const float* Wv = (const float*)d_in[5];
  const float* Wo = (const float*)d_in[6];
  float* out = (float*)d_out;

  char* ws = (char*)d_ws;
  const size_t MB = 1u << 20;
  u16* xb  = (u16*)(ws + 0 * MB);    // 16 MB
  u16* wqb = (u16*)(ws + 16 * MB);   // 8 MB (wq,wk,wv,wo contiguous)
  u16* wob = (u16*)(ws + 22 * MB);
  u16* qb  = (u16*)(ws + 24 * MB);   // 16 MB  [B,H,N,64]
  u16* kb  = (u16*)(ws + 40 * MB);   // 16 MB  [B,H,N,64]
  u16* vT  = (u16*)(ws + 56 * MB);   // 16 MB  [B,H,64,N]
  u16* ob  = (u16*)(ws + 72 * MB);   // 16 MB  [B,N,1024]
  u64* mbits = (u64*)(ws + 88 * MB); // 2 MB   [B*N][32]

  cast_f32_bf16<<<8192, 256, 0, stream>>>(x, xb, MTOT * DMODEL);
  cast_w4<<<4096, 256, 0, stream>>>(Wq, Wk, Wv, Wo, wqb);
  pack_mask<<<2048, 256, 0, stream>>>(mask, mbits);

  gemm_qkv<<<dim3(64, 24), 256, 0, stream>>>(xb, wqb, qb, kb, vT);

  attn_kernel<<<1024, 256, 0, stream>>>(qb, kb, vT, alibi, mbits, ob);

  gemm_out<<<dim3(64, 8), 256, 0, stream>>>(ob, wob, out);
}

// Round 16
// 683.336 us; speedup vs baseline: 1.2840x; 1.2840x over previous
//
#include <hip/hip_runtime.h>

#define NSEQ 2048
#define DMODEL 1024
#define NHEAD 16
#define HDIM 64
#define NBATCH 4
#define MTOT 8192
#define ATT_SCALE 0.125f
#define LOG2E 1.4426950408889634f
#define SM_SHIFT 12.0f

typedef __bf16 bf16x8 __attribute__((ext_vector_type(8)));
typedef float f32x4 __attribute__((ext_vector_type(4)));
typedef unsigned int u32x4 __attribute__((ext_vector_type(4)));
typedef unsigned short u16;
typedef unsigned int u32;
typedef unsigned long long u64;

__device__ __forceinline__ u16 f2bf(float f) {
  u32 u = __builtin_bit_cast(u32, f);
  return (u16)((u + 0x7fffu + ((u >> 16) & 1u)) >> 16);
}

__device__ __forceinline__ void gload_lds16(const void* g, void* l) {
  __builtin_amdgcn_global_load_lds(
      (__attribute__((address_space(1))) const u32*)g,
      (__attribute__((address_space(3))) u32*)l, 16, 0, 0);
}

// ---------------- cast fp32 -> bf16 (x) ----------------
__global__ __launch_bounds__(256) void cast_f32_bf16(const float* __restrict__ in,
                                                     u16* __restrict__ out, int n) {
  int i = (blockIdx.x * 256 + threadIdx.x) * 4;
  if (i >= n) return;
  float4 v = *(const float4*)(in + i);
  ushort4 o;
  o.x = f2bf(v.x); o.y = f2bf(v.y); o.z = f2bf(v.z); o.w = f2bf(v.w);
  *(ushort4*)(out + i) = o;
}

// ---------------- cast 4 weights -> contiguous bf16 block ----------------
__global__ __launch_bounds__(256) void cast_w4(const float* __restrict__ a,
                                               const float* __restrict__ b,
                                               const float* __restrict__ c,
                                               const float* __restrict__ d,
                                               u16* __restrict__ out) {
  int bid = blockIdx.x;
  int which = bid >> 10, lb = bid & 1023;
  const float* src = (which == 0) ? a : (which == 1) ? b : (which == 2) ? c : d;
  int i = (lb * 256 + threadIdx.x) * 4;
  float4 v = *(const float4*)(src + i);
  ushort4 o;
  o.x = f2bf(v.x); o.y = f2bf(v.y); o.z = f2bf(v.z); o.w = f2bf(v.w);
  *(ushort4*)(out + (size_t)which * 1048576 + i) = o;
}

// ---------------- pack mask int32 -> bit per element ----------------
__global__ __launch_bounds__(256) void pack_mask(const int* __restrict__ mask,
                                                 u64* __restrict__ bits) {
  int wave = (blockIdx.x * 256 + threadIdx.x) >> 6;
  int lane = threadIdx.x & 63;
  const int* row = mask + (size_t)wave * NSEQ;
  u64* out = bits + (size_t)wave * 32;
  for (int c = 0; c < 32; ++c) {
    int v = row[c * 64 + lane];
    u64 bl = __ballot(v != 0);
    if (lane == 0) out[c] = bl;
  }
}

// ---------------- fused QKV GEMM: C[m,n] = sum_k A[m,k]*Wc[n,k], N=3072 ----------------
// bn 0..7 -> Q [B,H,N,64]; 8..15 -> K [B,H,N,64]; 16..23 -> V^T [B,H,64,NSEQ]
__global__ __launch_bounds__(256) void gemm_qkv(const u16* __restrict__ A,
                                                const u16* __restrict__ Wc,
                                                u16* __restrict__ qo,
                                                u16* __restrict__ ko,
                                                u16* __restrict__ vo) {
  __shared__ __align__(16) u16 Al[128 * 64];
  __shared__ __align__(16) u16 Bl[128 * 64];
  const int tid = threadIdx.x;
  const int w = tid >> 6, l = tid & 63;
  const int l15 = l & 15, l4 = l >> 4;
  const int bm = blockIdx.x, bn = blockIdx.y;
  const int wm = w >> 1, wn = w & 1;

  f32x4 acc[4][4] = {};

  for (int ks = 0; ks < 1024; ks += 64) {
    __syncthreads();
#pragma unroll
    for (int c = 0; c < 4; ++c) {
      int g = w * 256 + c * 64 + l;
      int row = g >> 3, gc = g & 7;
      int sgc = gc ^ (row & 7);
      gload_lds16(A + (size_t)(bm * 128 + row) * 1024 + ks + sgc * 8, &Al[g * 8]);
      gload_lds16(Wc + (size_t)(bn * 128 + row) * 1024 + ks + sgc * 8, &Bl[g * 8]);
    }
    __syncthreads();
#pragma unroll
    for (int kc = 0; kc < 2; ++kc) {
      bf16x8 af[4], bfr[4];
#pragma unroll
      for (int mi = 0; mi < 4; ++mi) {
        int row = wm * 64 + mi * 16 + l15;
        int gc2 = (kc * 4 + l4) ^ (row & 7);
        af[mi] = *(const bf16x8*)&Al[row * 64 + gc2 * 8];
      }
#pragma unroll
      for (int ni = 0; ni < 4; ++ni) {
        int row = wn * 64 + ni * 16 + l15;
        int gc2 = (kc * 4 + l4) ^ (row & 7);
        bfr[ni] = *(const bf16x8*)&Bl[row * 64 + gc2 * 8];
      }
#pragma unroll
      for (int mi = 0; mi < 4; ++mi)
#pragma unroll
        for (int ni = 0; ni < 4; ++ni)
          acc[mi][ni] = __builtin_amdgcn_mfma_f32_16x16x32_bf16(af[mi], bfr[ni],
                                                                acc[mi][ni], 0, 0, 0);
    }
  }

  const int which = bn >> 3;
#pragma unroll
  for (int mi = 0; mi < 4; ++mi)
#pragma unroll
    for (int ni = 0; ni < 4; ++ni)
#pragma unroll
      for (int r = 0; r < 4; ++r) {
        int m = bm * 128 + wm * 64 + mi * 16 + l4 * 4 + r;
        int n = (bn & 7) * 128 + wn * 64 + ni * 16 + l15;
        int b = m >> 11, row = m & 2047, h = n >> 6, d = n & 63;
        u16 val = f2bf(acc[mi][ni][r]);
        size_t bh = (size_t)(b * 16 + h);
        if (which == 0)      qo[(bh * NSEQ + row) * 64 + d] = val;
        else if (which == 1) ko[(bh * NSEQ + row) * 64 + d] = val;
        else                 vo[(bh * 64 + d) * NSEQ + row] = val;
      }
}

// ---------------- final GEMM: out[m,n] = sum_k A[m,k]*W[n,k], fp32 out ----------------
__global__ __launch_bounds__(256) void gemm_out(const u16* __restrict__ A,
                                                const u16* __restrict__ W,
                                                float* __restrict__ C) {
  __shared__ __align__(16) u16 Al[128 * 64];
  __shared__ __align__(16) u16 Bl[128 * 64];
  const int tid = threadIdx.x;
  const int w = tid >> 6, l = tid & 63;
  const int l15 = l & 15, l4 = l >> 4;
  const int bm = blockIdx.x, bn = blockIdx.y;
  const int wm = w >> 1, wn = w & 1;

  f32x4 acc[4][4] = {};

  for (int ks = 0; ks < 1024; ks += 64) {
    __syncthreads();
#pragma unroll
    for (int c = 0; c < 4; ++c) {
      int g = w * 256 + c * 64 + l;
      int row = g >> 3, gc = g & 7;
      int sgc = gc ^ (row & 7);
      gload_lds16(A + (size_t)(bm * 128 + row) * 1024 + ks + sgc * 8, &Al[g * 8]);
      gload_lds16(W + (size_t)(bn * 128 + row) * 1024 + ks + sgc * 8, &Bl[g * 8]);
    }
    __syncthreads();
#pragma unroll
    for (int kc = 0; kc < 2; ++kc) {
      bf16x8 af[4], bfr[4];
#pragma unroll
      for (int mi = 0; mi < 4; ++mi) {
        int row = wm * 64 + mi * 16 + l15;
        int gc2 = (kc * 4 + l4) ^ (row & 7);
        af[mi] = *(const bf16x8*)&Al[row * 64 + gc2 * 8];
      }
#pragma unroll
      for (int ni = 0; ni < 4; ++ni) {
        int row = wn * 64 + ni * 16 + l15;
        int gc2 = (kc * 4 + l4) ^ (row & 7);
        bfr[ni] = *(const bf16x8*)&Bl[row * 64 + gc2 * 8];
      }
#pragma unroll
      for (int mi = 0; mi < 4; ++mi)
#pragma unroll
        for (int ni = 0; ni < 4; ++ni)
          acc[mi][ni] = __builtin_amdgcn_mfma_f32_16x16x32_bf16(af[mi], bfr[ni],
                                                                acc[mi][ni], 0, 0, 0);
    }
  }

#pragma unroll
  for (int mi = 0; mi < 4; ++mi)
#pragma unroll
    for (int ni = 0; ni < 4; ++ni)
#pragma unroll
      for (int r = 0; r < 4; ++r) {
        int m = bm * 128 + wm * 64 + mi * 16 + l4 * 4 + r;
        int n = bn * 128 + wn * 64 + ni * 16 + l15;
        C[(size_t)m * 1024 + n] = acc[mi][ni][r];
      }
}

// ---------------- flash attention (2 q-groups/wave, de-hoisted loads) ----------------
// 256 thr = 4 waves, grid 1024; each wave handles TWO 16-row q-groups ->
// 36 MFMA per stage+barrier (2x amortization), 2x K/V reuse. r15 verified the
// math; r15's 1.5 GB spill came from 64 VGPR of HOISTED K/V fragments + 16
// VGPR of cross-group alibi. Fix: each GROUP loads its own alibi/mask and
// reads K/V fragments from LDS right before each MFMA (r10's pattern) -- no
// long-lived transients, nothing new across the barrier. Fixed-shift softmax
// + ones-trick row-sum; K staged row-permuted; V contiguous b128;
// batch-innermost XCD decode.
__global__ __launch_bounds__(256, 4) void attn_kernel(
    const u16* __restrict__ q, const u16* __restrict__ k, const u16* __restrict__ vT,
    const float* __restrict__ alibi, const u64* __restrict__ mbits,
    u16* __restrict__ o) {
  __shared__ __align__(16) u16 Kl[2][64 * 64];
  __shared__ __align__(16) u16 Vl[2][64 * 64];

  const int tid = threadIdx.x, w = tid >> 6, l = tid & 63;
  const int l15 = l & 15, l4 = l >> 4;
  const int W = blockIdx.x;
  // 1024 = 8 XCD * 128; batch innermost for alibi L2 reuse
  const int W2 = (W & 7) * 128 + (W >> 3);
  const int b = W2 & 3, hq = W2 >> 2;
  const int qb = hq & 15, h = hq >> 4;
  const int bh = b * 16 + h;
  const int wq0 = qb * 128 + w * 16;      // group0 rows [wq0, wq0+16)
  const int myq0 = wq0 + l15;             // group1 rows [wq0+64, wq0+80)
  const int myq1 = wq0 + 64 + l15;

  // Q fragments for both groups (B-operand: col q = l15)
  bf16x8 aq0, aq1, aq2, aq3;
  {
    const u16* qrow0 = q + ((size_t)bh * NSEQ + myq0) * 64;
    aq0 = *(const bf16x8*)(qrow0 + l4 * 8);
    aq1 = *(const bf16x8*)(qrow0 + 32 + l4 * 8);
    const u16* qrow1 = q + ((size_t)bh * NSEQ + myq1) * 64;
    aq2 = *(const bf16x8*)(qrow1 + l4 * 8);
    aq3 = *(const bf16x8*)(qrow1 + 32 + l4 * 8);
  }

  // staging pointers. K rows permuted: LDS row p holds global row
  // 32*(p>>5) + 8*((p>>2)&3) + 4*((p>>4)&1) + (p&3)
  const u16* kg[2]; const u16* vg[2];
#pragma unroll
  for (int c = 0; c < 2; ++c) {
    int g = w * 128 + c * 64 + l;
    int row = g >> 3, gc = g & 7, sgc = gc ^ (row & 7);
    int srow = (row & 0x23) | (((row >> 2) & 3) << 3) | (((row >> 4) & 1) << 2);
    kg[c] = k + ((size_t)bh * NSEQ + srow) * 64 + sgc * 8;
    vg[c] = vT + ((size_t)bh * 64 + row) * NSEQ + sgc * 8;
  }

  // per-lane alibi / mask pointers for both q-groups
  const float* alp0 = alibi + (size_t)h * NSEQ * NSEQ + (size_t)myq0 * NSEQ + 8 * l4;
  const float* alp1 = alibi + (size_t)h * NSEQ * NSEQ + (size_t)myq1 * NSEQ + 8 * l4;
  const u64* mrp0 = mbits + ((size_t)b * NSEQ + myq0) * 32;
  const u64* mrp1 = mbits + ((size_t)b * NSEQ + myq1) * 32;

  // LDS read offsets (K and V identical pattern, conflict-free b128)
  const int kfr0 = l15 * 128 + (((0 + l4) ^ (l15 & 7)) << 4);
  const int kfr1 = l15 * 128 + (((4 + l4) ^ (l15 & 7)) << 4);

  const u32x4 onesu = {0x3F803F80u, 0x3F803F80u, 0x3F803F80u, 0x3F803F80u};
  const bf16x8 bones = __builtin_bit_cast(bf16x8, onesu);

  f32x4 oaccA[4] = {};  // group0: q = wq0 + l4*4 + r, d = db*16 + l15
  f32x4 oaccB[4] = {};  // group1: q = wq0 + 64 + l4*4 + r
  f32x4 osumA = {}, osumB = {};

  auto stage = [&](u16* KB, u16* VB) {
#pragma unroll
    for (int c = 0; c < 2; ++c) {
      gload_lds16(kg[c], (char*)KB + (w * 128 + c * 64 + l) * 16);
      kg[c] += 4096;
      gload_lds16(vg[c], (char*)VB + (w * 128 + c * 64 + l) * 16);
      vg[c] += 64;
    }
  };

  stage(Kl[0], Vl[0]);
  __syncthreads();

  // One q-group: loads its own alibi/mask, reads K/V from LDS just-in-time.
  // (kb,r) -> global k = 32*(kb>>1) + 8*l4 + 4*(kb&1) + r (K-row permutation)
#define GROUP(KB, VB, AQ0, AQ1, ALP, MRP, OSUM, OACC, t)                       \
  {                                                                            \
    float4 A0 = *(const float4*)((ALP) + (t) * 64);                            \
    float4 A1 = *(const float4*)((ALP) + (t) * 64 + 4);                        \
    float4 A2 = *(const float4*)((ALP) + (t) * 64 + 32);                       \
    float4 A3 = *(const float4*)((ALP) + (t) * 64 + 36);                       \
    u64 mb = (MRP)[t];                                                         \
    f32x4 st[4];                                                               \
    _Pragma("unroll")                                                          \
    for (int kb = 0; kb < 4; ++kb) {                                           \
      f32x4 z = {0.f, 0.f, 0.f, 0.f};                                          \
      st[kb] = z;                                                              \
      bf16x8 bk = *(const bf16x8*)((const char*)(KB) + kfr0 + kb * 2048);      \
      st[kb] = __builtin_amdgcn_mfma_f32_16x16x32_bf16(bk, AQ0, st[kb], 0, 0, 0); \
      bk = *(const bf16x8*)((const char*)(KB) + kfr1 + kb * 2048);             \
      st[kb] = __builtin_amdgcn_mfma_f32_16x16x32_bf16(bk, AQ1, st[kb], 0, 0, 0); \
    }                                                                          \
    st[0][0] = fmaf(st[0][0], ATT_SCALE, A0.x);                                \
    st[0][1] = fmaf(st[0][1], ATT_SCALE, A0.y);                                \
    st[0][2] = fmaf(st[0][2], ATT_SCALE, A0.z);                                \
    st[0][3] = fmaf(st[0][3], ATT_SCALE, A0.w);                                \
    st[1][0] = fmaf(st[1][0], ATT_SCALE, A1.x);                                \
    st[1][1] = fmaf(st[1][1], ATT_SCALE, A1.y);                                \
    st[1][2] = fmaf(st[1][2], ATT_SCALE, A1.z);                                \
    st[1][3] = fmaf(st[1][3], ATT_SCALE, A1.w);                                \
    st[2][0] = fmaf(st[2][0], ATT_SCALE, A2.x);                                \
    st[2][1] = fmaf(st[2][1], ATT_SCALE, A2.y);                                \
    st[2][2] = fmaf(st[2][2], ATT_SCALE, A2.z);                                \
    st[2][3] = fmaf(st[2][3], ATT_SCALE, A2.w);                                \
    st[3][0] = fmaf(st[3][0], ATT_SCALE, A3.x);                                \
    st[3][1] = fmaf(st[3][1], ATT_SCALE, A3.y);                                \
    st[3][2] = fmaf(st[3][2], ATT_SCALE, A3.z);                                \
    st[3][3] = fmaf(st[3][3], ATT_SCALE, A3.w);                                \
    if (!__all(mb == ~0ull)) {                                                 \
      _Pragma("unroll")                                                        \
      for (int r = 0; r < 4; ++r) {                                            \
        if (!((mb >> (8 * l4 + r)) & 1))      st[0][r] = -3.0e38f;             \
        if (!((mb >> (8 * l4 + 4 + r)) & 1))  st[1][r] = -3.0e38f;             \
        if (!((mb >> (32 + 8 * l4 + r)) & 1)) st[2][r] = -3.0e38f;             \
        if (!((mb >> (36 + 8 * l4 + r)) & 1)) st[3][r] = -3.0e38f;             \
      }                                                                        \
    }                                                                          \
    float p[16];                                                               \
    _Pragma("unroll")                                                          \
    for (int kb = 0; kb < 4; ++kb)                                             \
      _Pragma("unroll")                                                        \
      for (int r = 0; r < 4; ++r)                                              \
        p[kb * 4 + r] = exp2f(fmaf(st[kb][r], LOG2E, -SM_SHIFT * LOG2E));      \
    u32 Wp[8];                                                                 \
    _Pragma("unroll")                                                          \
    for (int i = 0; i < 8; ++i)                                                \
      asm("v_cvt_pk_bf16_f32 %0, %1, %2" : "=v"(Wp[i]) : "v"(p[2 * i]), "v"(p[2 * i + 1])); \
    {                                                                          \
      u32x4 wv0 = {Wp[0], Wp[1], Wp[2], Wp[3]};                                \
      bf16x8 pa = __builtin_bit_cast(bf16x8, wv0);                             \
      OSUM = __builtin_amdgcn_mfma_f32_16x16x32_bf16(pa, bones, OSUM, 0, 0, 0);\
      _Pragma("unroll")                                                        \
      for (int db = 0; db < 4; ++db) {                                         \
        bf16x8 bv = *(const bf16x8*)((const char*)(VB) + kfr0 + db * 2048);    \
        OACC[db] = __builtin_amdgcn_mfma_f32_16x16x32_bf16(pa, bv, OACC[db], 0, 0, 0); \
      }                                                                        \
      u32x4 wv1 = {Wp[4], Wp[5], Wp[6], Wp[7]};                                \
      pa = __builtin_bit_cast(bf16x8, wv1);                                    \
      OSUM = __builtin_amdgcn_mfma_f32_16x16x32_bf16(pa, bones, OSUM, 0, 0, 0);\
      _Pragma("unroll")                                                        \
      for (int db = 0; db < 4; ++db) {                                         \
        bf16x8 bv = *(const bf16x8*)((const char*)(VB) + kfr1 + db * 2048);    \
        OACC[db] = __builtin_amdgcn_mfma_f32_16x16x32_bf16(pa, bv, OACC[db], 0, 0, 0); \
      }                                                                        \
    }                                                                          \
  }

  auto body = [&](const u16* KB, const u16* VB, u16* KN, u16* VN, int t, bool dost) {
    if (dost) stage(KN, VN);
    GROUP(KB, VB, aq0, aq1, alp0, mrp0, osumA, oaccA, t)
    GROUP(KB, VB, aq2, aq3, alp1, mrp1, osumB, oaccB, t)
    __syncthreads();
  };

  for (int t2 = 0; t2 < 16; ++t2) {
    body(Kl[0], Vl[0], Kl[1], Vl[1], t2 * 2, true);
    body(Kl[1], Vl[1], Kl[0], Vl[0], t2 * 2 + 1, t2 < 15);
  }
#undef GROUP

  // normalize + write O for both groups; shfl-free
#pragma unroll
  for (int r = 0; r < 4; ++r) {
    float invA = __builtin_amdgcn_rcpf(osumA[r]);
    int qq = wq0 + l4 * 4 + r;
    u16* orow = o + ((size_t)b * NSEQ + qq) * DMODEL + h * 64 + l15;
    orow[0]  = f2bf(oaccA[0][r] * invA);
    orow[16] = f2bf(oaccA[1][r] * invA);
    orow[32] = f2bf(oaccA[2][r] * invA);
    orow[48] = f2bf(oaccA[3][r] * invA);
    float invB = __builtin_amdgcn_rcpf(osumB[r]);
    u16* orow2 = o + ((size_t)b * NSEQ + qq + 64) * DMODEL + h * 64 + l15;
    orow2[0]  = f2bf(oaccB[0][r] * invB);
    orow2[16] = f2bf(oaccB[1][r] * invB);
    orow2[32] = f2bf(oaccB[2][r] * invB);
    orow2[48] = f2bf(oaccB[3][r] * invB);
  }
}

extern "C" void kernel_launch(void* const* d_in, const int* in_sizes, int n_in,
                              void* d_out, int out_size, void* d_ws, size_t ws_size,
                              hipStream_t stream) {
  (void)in_sizes; (void)n_in; (void)out_size; (void)ws_size;
  const float* x = (const float*)d_in[0];
  const int* mask = (const int*)d_in[1];
  const float* alibi = (const float*)d_in[2];
  const float* Wq = (const float*)d_in[3];
  const float* Wk = (const float*)d_in[4];
  const float* Wv = (const float*)d_in[5];
  const float* Wo = (const float*)d_in[6];
  float* out = (float*)d_out;

  char* ws = (char*)d_ws;
  const size_t MB = 1u << 20;
  u16* xb  = (u16*)(ws + 0 * MB);    // 16 MB
  u16* wqb = (u16*)(ws + 16 * MB);   // 8 MB (wq,wk,wv,wo contiguous)
  u16* wob = (u16*)(ws + 22 * MB);
  u16* qb  = (u16*)(ws + 24 * MB);   // 16 MB  [B,H,N,64]
  u16* kb  = (u16*)(ws + 40 * MB);   // 16 MB  [B,H,N,64]
  u16* vT  = (u16*)(ws + 56 * MB);   // 16 MB  [B,H,64,N]
  u16* ob  = (u16*)(ws + 72 * MB);   // 16 MB  [B,N,1024]
  u64* mbits = (u64*)(ws + 88 * MB); // 2 MB   [B*N][32]

  cast_f32_bf16<<<8192, 256, 0, stream>>>(x, xb, MTOT * DMODEL);
  cast_w4<<<4096, 256, 0, stream>>>(Wq, Wk, Wv, Wo, wqb);
  pack_mask<<<2048, 256, 0, stream>>>(mask, mbits);

  gemm_qkv<<<dim3(64, 24), 256, 0, stream>>>(xb, wqb, qb, kb, vT);

  attn_kernel<<<1024, 256, 0, stream>>>(qb, kb, vT, alibi, mbits, ob);

  gemm_out<<<dim3(64, 8), 256, 0, stream>>>(ob, wob, out);
}

// Round 17
// 355.445 us; speedup vs baseline: 2.4685x; 1.9225x over previous
//
#include <hip/hip_runtime.h>

#define NSEQ 2048
#define DMODEL 1024
#define NHEAD 16
#define HDIM 64
#define NBATCH 4
#define MTOT 8192
#define ATT_SCALE 0.125f
#define LOG2E 1.4426950408889634f
#define SM_SHIFT 12.0f

typedef __bf16 bf16x8 __attribute__((ext_vector_type(8)));
typedef float f32x4 __attribute__((ext_vector_type(4)));
typedef unsigned int u32x4 __attribute__((ext_vector_type(4)));
typedef unsigned short u16;
typedef unsigned int u32;
typedef unsigned long long u64;

__device__ __forceinline__ u16 f2bf(float f) {
  u32 u = __builtin_bit_cast(u32, f);
  return (u16)((u + 0x7fffu + ((u >> 16) & 1u)) >> 16);
}

__device__ __forceinline__ void gload_lds16(const void* g, void* l) {
  __builtin_amdgcn_global_load_lds(
      (__attribute__((address_space(1))) const u32*)g,
      (__attribute__((address_space(3))) u32*)l, 16, 0, 0);
}

// ---------------- cast fp32 -> bf16 (x) ----------------
__global__ __launch_bounds__(256) void cast_f32_bf16(const float* __restrict__ in,
                                                     u16* __restrict__ out, int n) {
  int i = (blockIdx.x * 256 + threadIdx.x) * 4;
  if (i >= n) return;
  float4 v = *(const float4*)(in + i);
  ushort4 o;
  o.x = f2bf(v.x); o.y = f2bf(v.y); o.z = f2bf(v.z); o.w = f2bf(v.w);
  *(ushort4*)(out + i) = o;
}

// ---------------- cast 4 weights -> contiguous bf16 block ----------------
__global__ __launch_bounds__(256) void cast_w4(const float* __restrict__ a,
                                               const float* __restrict__ b,
                                               const float* __restrict__ c,
                                               const float* __restrict__ d,
                                               u16* __restrict__ out) {
  int bid = blockIdx.x;
  int which = bid >> 10, lb = bid & 1023;
  const float* src = (which == 0) ? a : (which == 1) ? b : (which == 2) ? c : d;
  int i = (lb * 256 + threadIdx.x) * 4;
  float4 v = *(const float4*)(src + i);
  ushort4 o;
  o.x = f2bf(v.x); o.y = f2bf(v.y); o.z = f2bf(v.z); o.w = f2bf(v.w);
  *(ushort4*)(out + (size_t)which * 1048576 + i) = o;
}

// ---------------- pack mask int32 -> bit per element ----------------
__global__ __launch_bounds__(256) void pack_mask(const int* __restrict__ mask,
                                                 u64* __restrict__ bits) {
  int wave = (blockIdx.x * 256 + threadIdx.x) >> 6;
  int lane = threadIdx.x & 63;
  const int* row = mask + (size_t)wave * NSEQ;
  u64* out = bits + (size_t)wave * 32;
  for (int c = 0; c < 32; ++c) {
    int v = row[c * 64 + lane];
    u64 bl = __ballot(v != 0);
    if (lane == 0) out[c] = bl;
  }
}

// ---------------- fused QKV GEMM: C[m,n] = sum_k A[m,k]*Wc[n,k], N=3072 ----------------
// bn 0..7 -> Q [B,H,N,64]; 8..15 -> K [B,H,N,64]; 16..23 -> V^T [B,H,64,NSEQ]
__global__ __launch_bounds__(256) void gemm_qkv(const u16* __restrict__ A,
                                                const u16* __restrict__ Wc,
                                                u16* __restrict__ qo,
                                                u16* __restrict__ ko,
                                                u16* __restrict__ vo) {
  __shared__ __align__(16) u16 Al[128 * 64];
  __shared__ __align__(16) u16 Bl[128 * 64];
  const int tid = threadIdx.x;
  const int w = tid >> 6, l = tid & 63;
  const int l15 = l & 15, l4 = l >> 4;
  const int bm = blockIdx.x, bn = blockIdx.y;
  const int wm = w >> 1, wn = w & 1;

  f32x4 acc[4][4] = {};

  for (int ks = 0; ks < 1024; ks += 64) {
    __syncthreads();
#pragma unroll
    for (int c = 0; c < 4; ++c) {
      int g = w * 256 + c * 64 + l;
      int row = g >> 3, gc = g & 7;
      int sgc = gc ^ (row & 7);
      gload_lds16(A + (size_t)(bm * 128 + row) * 1024 + ks + sgc * 8, &Al[g * 8]);
      gload_lds16(Wc + (size_t)(bn * 128 + row) * 1024 + ks + sgc * 8, &Bl[g * 8]);
    }
    __syncthreads();
#pragma unroll
    for (int kc = 0; kc < 2; ++kc) {
      bf16x8 af[4], bfr[4];
#pragma unroll
      for (int mi = 0; mi < 4; ++mi) {
        int row = wm * 64 + mi * 16 + l15;
        int gc2 = (kc * 4 + l4) ^ (row & 7);
        af[mi] = *(const bf16x8*)&Al[row * 64 + gc2 * 8];
      }
#pragma unroll
      for (int ni = 0; ni < 4; ++ni) {
        int row = wn * 64 + ni * 16 + l15;
        int gc2 = (kc * 4 + l4) ^ (row & 7);
        bfr[ni] = *(const bf16x8*)&Bl[row * 64 + gc2 * 8];
      }
#pragma unroll
      for (int mi = 0; mi < 4; ++mi)
#pragma unroll
        for (int ni = 0; ni < 4; ++ni)
          acc[mi][ni] = __builtin_amdgcn_mfma_f32_16x16x32_bf16(af[mi], bfr[ni],
                                                                acc[mi][ni], 0, 0, 0);
    }
  }

  const int which = bn >> 3;
#pragma unroll
  for (int mi = 0; mi < 4; ++mi)
#pragma unroll
    for (int ni = 0; ni < 4; ++ni)
#pragma unroll
      for (int r = 0; r < 4; ++r) {
        int m = bm * 128 + wm * 64 + mi * 16 + l4 * 4 + r;
        int n = (bn & 7) * 128 + wn * 64 + ni * 16 + l15;
        int b = m >> 11, row = m & 2047, h = n >> 6, d = n & 63;
        u16 val = f2bf(acc[mi][ni][r]);
        size_t bh = (size_t)(b * 16 + h);
        if (which == 0)      qo[(bh * NSEQ + row) * 64 + d] = val;
        else if (which == 1) ko[(bh * NSEQ + row) * 64 + d] = val;
        else                 vo[(bh * 64 + d) * NSEQ + row] = val;
      }
}

// ---------------- final GEMM: out[m,n] = sum_k A[m,k]*W[n,k], fp32 out ----------------
__global__ __launch_bounds__(256) void gemm_out(const u16* __restrict__ A,
                                                const u16* __restrict__ W,
                                                float* __restrict__ C) {
  __shared__ __align__(16) u16 Al[128 * 64];
  __shared__ __align__(16) u16 Bl[128 * 64];
  const int tid = threadIdx.x;
  const int w = tid >> 6, l = tid & 63;
  const int l15 = l & 15, l4 = l >> 4;
  const int bm = blockIdx.x, bn = blockIdx.y;
  const int wm = w >> 1, wn = w & 1;

  f32x4 acc[4][4] = {};

  for (int ks = 0; ks < 1024; ks += 64) {
    __syncthreads();
#pragma unroll
    for (int c = 0; c < 4; ++c) {
      int g = w * 256 + c * 64 + l;
      int row = g >> 3, gc = g & 7;
      int sgc = gc ^ (row & 7);
      gload_lds16(A + (size_t)(bm * 128 + row) * 1024 + ks + sgc * 8, &Al[g * 8]);
      gload_lds16(W + (size_t)(bn * 128 + row) * 1024 + ks + sgc * 8, &Bl[g * 8]);
    }
    __syncthreads();
#pragma unroll
    for (int kc = 0; kc < 2; ++kc) {
      bf16x8 af[4], bfr[4];
#pragma unroll
      for (int mi = 0; mi < 4; ++mi) {
        int row = wm * 64 + mi * 16 + l15;
        int gc2 = (kc * 4 + l4) ^ (row & 7);
        af[mi] = *(const bf16x8*)&Al[row * 64 + gc2 * 8];
      }
#pragma unroll
      for (int ni = 0; ni < 4; ++ni) {
        int row = wn * 64 + ni * 16 + l15;
        int gc2 = (kc * 4 + l4) ^ (row & 7);
        bfr[ni] = *(const bf16x8*)&Bl[row * 64 + gc2 * 8];
      }
#pragma unroll
      for (int mi = 0; mi < 4; ++mi)
#pragma unroll
        for (int ni = 0; ni < 4; ++ni)
          acc[mi][ni] = __builtin_amdgcn_mfma_f32_16x16x32_bf16(af[mi], bfr[ni],
                                                                acc[mi][ni], 0, 0, 0);
    }
  }

#pragma unroll
  for (int mi = 0; mi < 4; ++mi)
#pragma unroll
    for (int ni = 0; ni < 4; ++ni)
#pragma unroll
      for (int r = 0; r < 4; ++r) {
        int m = bm * 128 + wm * 64 + mi * 16 + l4 * 4 + r;
        int n = bn * 128 + wn * 64 + ni * 16 + l15;
        C[(size_t)m * 1024 + n] = acc[mi][ni][r];
      }
}

// ---------------- flash attention (2 q-groups/wave, relaxed register bound) ----------------
// Identical to r16 except __launch_bounds__(256, 2): the 2-group schedule
// needs ~110 live registers; bound=4 capped the unified budget at 128 (~88
// arch after AGPRs) and the allocator responded with 64+spill (WRITE 986 MB).
// bound=2 doubles the budget to 256. If this still spills, the line is dead
// and r14 stands. 36 MFMA per stage+barrier, 2x K/V reuse, fixed-shift
// softmax + ones-trick row-sum, K-row permutation, conflict-free b128 V,
// batch-innermost XCD decode.
__global__ __launch_bounds__(256, 2) void attn_kernel(
    const u16* __restrict__ q, const u16* __restrict__ k, const u16* __restrict__ vT,
    const float* __restrict__ alibi, const u64* __restrict__ mbits,
    u16* __restrict__ o) {
  __shared__ __align__(16) u16 Kl[2][64 * 64];
  __shared__ __align__(16) u16 Vl[2][64 * 64];

  const int tid = threadIdx.x, w = tid >> 6, l = tid & 63;
  const int l15 = l & 15, l4 = l >> 4;
  const int W = blockIdx.x;
  // 1024 = 8 XCD * 128; batch innermost for alibi L2 reuse
  const int W2 = (W & 7) * 128 + (W >> 3);
  const int b = W2 & 3, hq = W2 >> 2;
  const int qb = hq & 15, h = hq >> 4;
  const int bh = b * 16 + h;
  const int wq0 = qb * 128 + w * 16;      // group0 rows [wq0, wq0+16)
  const int myq0 = wq0 + l15;             // group1 rows [wq0+64, wq0+80)
  const int myq1 = wq0 + 64 + l15;

  // Q fragments for both groups (B-operand: col q = l15)
  bf16x8 aq0, aq1, aq2, aq3;
  {
    const u16* qrow0 = q + ((size_t)bh * NSEQ + myq0) * 64;
    aq0 = *(const bf16x8*)(qrow0 + l4 * 8);
    aq1 = *(const bf16x8*)(qrow0 + 32 + l4 * 8);
    const u16* qrow1 = q + ((size_t)bh * NSEQ + myq1) * 64;
    aq2 = *(const bf16x8*)(qrow1 + l4 * 8);
    aq3 = *(const bf16x8*)(qrow1 + 32 + l4 * 8);
  }

  // staging pointers. K rows permuted: LDS row p holds global row
  // 32*(p>>5) + 8*((p>>2)&3) + 4*((p>>4)&1) + (p&3)
  const u16* kg[2]; const u16* vg[2];
#pragma unroll
  for (int c = 0; c < 2; ++c) {
    int g = w * 128 + c * 64 + l;
    int row = g >> 3, gc = g & 7, sgc = gc ^ (row & 7);
    int srow = (row & 0x23) | (((row >> 2) & 3) << 3) | (((row >> 4) & 1) << 2);
    kg[c] = k + ((size_t)bh * NSEQ + srow) * 64 + sgc * 8;
    vg[c] = vT + ((size_t)bh * 64 + row) * NSEQ + sgc * 8;
  }

  // per-lane alibi / mask pointers for both q-groups
  const float* alp0 = alibi + (size_t)h * NSEQ * NSEQ + (size_t)myq0 * NSEQ + 8 * l4;
  const float* alp1 = alibi + (size_t)h * NSEQ * NSEQ + (size_t)myq1 * NSEQ + 8 * l4;
  const u64* mrp0 = mbits + ((size_t)b * NSEQ + myq0) * 32;
  const u64* mrp1 = mbits + ((size_t)b * NSEQ + myq1) * 32;

  // LDS read offsets (K and V identical pattern, conflict-free b128)
  const int kfr0 = l15 * 128 + (((0 + l4) ^ (l15 & 7)) << 4);
  const int kfr1 = l15 * 128 + (((4 + l4) ^ (l15 & 7)) << 4);

  const u32x4 onesu = {0x3F803F80u, 0x3F803F80u, 0x3F803F80u, 0x3F803F80u};
  const bf16x8 bones = __builtin_bit_cast(bf16x8, onesu);

  f32x4 oaccA[4] = {};  // group0: q = wq0 + l4*4 + r, d = db*16 + l15
  f32x4 oaccB[4] = {};  // group1: q = wq0 + 64 + l4*4 + r
  f32x4 osumA = {}, osumB = {};

  auto stage = [&](u16* KB, u16* VB) {
#pragma unroll
    for (int c = 0; c < 2; ++c) {
      gload_lds16(kg[c], (char*)KB + (w * 128 + c * 64 + l) * 16);
      kg[c] += 4096;
      gload_lds16(vg[c], (char*)VB + (w * 128 + c * 64 + l) * 16);
      vg[c] += 64;
    }
  };

  stage(Kl[0], Vl[0]);
  __syncthreads();

  // One q-group: loads its own alibi/mask, reads K/V from LDS just-in-time.
  // (kb,r) -> global k = 32*(kb>>1) + 8*l4 + 4*(kb&1) + r (K-row permutation)
#define GROUP(KB, VB, AQ0, AQ1, ALP, MRP, OSUM, OACC, t)                       \
  {                                                                            \
    float4 A0 = *(const float4*)((ALP) + (t) * 64);                            \
    float4 A1 = *(const float4*)((ALP) + (t) * 64 + 4);                        \
    float4 A2 = *(const float4*)((ALP) + (t) * 64 + 32);                       \
    float4 A3 = *(const float4*)((ALP) + (t) * 64 + 36);                       \
    u64 mb = (MRP)[t];                                                         \
    f32x4 st[4];                                                               \
    _Pragma("unroll")                                                          \
    for (int kb = 0; kb < 4; ++kb) {                                           \
      f32x4 z = {0.f, 0.f, 0.f, 0.f};                                          \
      st[kb] = z;                                                              \
      bf16x8 bk = *(const bf16x8*)((const char*)(KB) + kfr0 + kb * 2048);      \
      st[kb] = __builtin_amdgcn_mfma_f32_16x16x32_bf16(bk, AQ0, st[kb], 0, 0, 0); \
      bk = *(const bf16x8*)((const char*)(KB) + kfr1 + kb * 2048);             \
      st[kb] = __builtin_amdgcn_mfma_f32_16x16x32_bf16(bk, AQ1, st[kb], 0, 0, 0); \
    }                                                                          \
    st[0][0] = fmaf(st[0][0], ATT_SCALE, A0.x);                                \
    st[0][1] = fmaf(st[0][1], ATT_SCALE, A0.y);                                \
    st[0][2] = fmaf(st[0][2], ATT_SCALE, A0.z);                                \
    st[0][3] = fmaf(st[0][3], ATT_SCALE, A0.w);                                \
    st[1][0] = fmaf(st[1][0], ATT_SCALE, A1.x);                                \
    st[1][1] = fmaf(st[1][1], ATT_SCALE, A1.y);                                \
    st[1][2] = fmaf(st[1][2], ATT_SCALE, A1.z);                                \
    st[1][3] = fmaf(st[1][3], ATT_SCALE, A1.w);                                \
    st[2][0] = fmaf(st[2][0], ATT_SCALE, A2.x);                                \
    st[2][1] = fmaf(st[2][1], ATT_SCALE, A2.y);                                \
    st[2][2] = fmaf(st[2][2], ATT_SCALE, A2.z);                                \
    st[2][3] = fmaf(st[2][3], ATT_SCALE, A2.w);                                \
    st[3][0] = fmaf(st[3][0], ATT_SCALE, A3.x);                                \
    st[3][1] = fmaf(st[3][1], ATT_SCALE, A3.y);                                \
    st[3][2] = fmaf(st[3][2], ATT_SCALE, A3.z);                                \
    st[3][3] = fmaf(st[3][3], ATT_SCALE, A3.w);                                \
    if (!__all(mb == ~0ull)) {                                                 \
      _Pragma("unroll")                                                        \
      for (int r = 0; r < 4; ++r) {                                            \
        if (!((mb >> (8 * l4 + r)) & 1))      st[0][r] = -3.0e38f;             \
        if (!((mb >> (8 * l4 + 4 + r)) & 1))  st[1][r] = -3.0e38f;             \
        if (!((mb >> (32 + 8 * l4 + r)) & 1)) st[2][r] = -3.0e38f;             \
        if (!((mb >> (36 + 8 * l4 + r)) & 1)) st[3][r] = -3.0e38f;             \
      }                                                                        \
    }                                                                          \
    float p[16];                                                               \
    _Pragma("unroll")                                                          \
    for (int kb = 0; kb < 4; ++kb)                                             \
      _Pragma("unroll")                                                        \
      for (int r = 0; r < 4; ++r)                                              \
        p[kb * 4 + r] = exp2f(fmaf(st[kb][r], LOG2E, -SM_SHIFT * LOG2E));      \
    u32 Wp[8];                                                                 \
    _Pragma("unroll")                                                          \
    for (int i = 0; i < 8; ++i)                                                \
      asm("v_cvt_pk_bf16_f32 %0, %1, %2" : "=v"(Wp[i]) : "v"(p[2 * i]), "v"(p[2 * i + 1])); \
    {                                                                          \
      u32x4 wv0 = {Wp[0], Wp[1], Wp[2], Wp[3]};                                \
      bf16x8 pa = __builtin_bit_cast(bf16x8, wv0);                             \
      OSUM = __builtin_amdgcn_mfma_f32_16x16x32_bf16(pa, bones, OSUM, 0, 0, 0);\
      _Pragma("unroll")                                                        \
      for (int db = 0; db < 4; ++db) {                                         \
        bf16x8 bv = *(const bf16x8*)((const char*)(VB) + kfr0 + db * 2048);    \
        OACC[db] = __builtin_amdgcn_mfma_f32_16x16x32_bf16(pa, bv, OACC[db], 0, 0, 0); \
      }                                                                        \
      u32x4 wv1 = {Wp[4], Wp[5], Wp[6], Wp[7]};                                \
      pa = __builtin_bit_cast(bf16x8, wv1);                                    \
      OSUM = __builtin_amdgcn_mfma_f32_16x16x32_bf16(pa, bones, OSUM, 0, 0, 0);\
      _Pragma("unroll")                                                        \
      for (int db = 0; db < 4; ++db) {                                         \
        bf16x8 bv = *(const bf16x8*)((const char*)(VB) + kfr1 + db * 2048);    \
        OACC[db] = __builtin_amdgcn_mfma_f32_16x16x32_bf16(pa, bv, OACC[db], 0, 0, 0); \
      }                                                                        \
    }                                                                          \
  }

  auto body = [&](const u16* KB, const u16* VB, u16* KN, u16* VN, int t, bool dost) {
    if (dost) stage(KN, VN);
    GROUP(KB, VB, aq0, aq1, alp0, mrp0, osumA, oaccA, t)
    GROUP(KB, VB, aq2, aq3, alp1, mrp1, osumB, oaccB, t)
    __syncthreads();
  };

  for (int t2 = 0; t2 < 16; ++t2) {
    body(Kl[0], Vl[0], Kl[1], Vl[1], t2 * 2, true);
    body(Kl[1], Vl[1], Kl[0], Vl[0], t2 * 2 + 1, t2 < 15);
  }
#undef GROUP

  // normalize + write O for both groups; shfl-free
#pragma unroll
  for (int r = 0; r < 4; ++r) {
    float invA = __builtin_amdgcn_rcpf(osumA[r]);
    int qq = wq0 + l4 * 4 + r;
    u16* orow = o + ((size_t)b * NSEQ + qq) * DMODEL + h * 64 + l15;
    orow[0]  = f2bf(oaccA[0][r] * invA);
    orow[16] = f2bf(oaccA[1][r] * invA);
    orow[32] = f2bf(oaccA[2][r] * invA);
    orow[48] = f2bf(oaccA[3][r] * invA);
    float invB = __builtin_amdgcn_rcpf(osumB[r]);
    u16* orow2 = o + ((size_t)b * NSEQ + qq + 64) * DMODEL + h * 64 + l15;
    orow2[0]  = f2bf(oaccB[0][r] * invB);
    orow2[16] = f2bf(oaccB[1][r] * invB);
    orow2[32] = f2bf(oaccB[2][r] * invB);
    orow2[48] = f2bf(oaccB[3][r] * invB);
  }
}

extern "C" void kernel_launch(void* const* d_in, const int* in_sizes, int n_in,
                              void* d_out, int out_size, void* d_ws, size_t ws_size,
                              hipStream_t stream) {
  (void)in_sizes; (void)n_in; (void)out_size; (void)ws_size;
  const float* x = (const float*)d_in[0];
  const int* mask = (const int*)d_in[1];
  const float* alibi = (const float*)d_in[2];
  const float* Wq = (const float*)d_in[3];
  const float* Wk = (const float*)d_in[4];
  const float* Wv = (const float*)d_in[5];
  const float* Wo = (const float*)d_in[6];
  float* out = (float*)d_out;

  char* ws = (char*)d_ws;
  const size_t MB = 1u << 20;
  u16* xb  = (u16*)(ws + 0 * MB);    // 16 MB
  u16* wqb = (u16*)(ws + 16 * MB);   // 8 MB (wq,wk,wv,wo contiguous)
  u16* wob = (u16*)(ws + 22 * MB);
  u16* qb  = (u16*)(ws + 24 * MB);   // 16 MB  [B,H,N,64]
  u16* kb  = (u16*)(ws + 40 * MB);   // 16 MB  [B,H,N,64]
  u16* vT  = (u16*)(ws + 56 * MB);   // 16 MB  [B,H,64,N]
  u16* ob  = (u16*)(ws + 72 * MB);   // 16 MB  [B,N,1024]
  u64* mbits = (u64*)(ws + 88 * MB); // 2 MB   [B*N][32]

  cast_f32_bf16<<<8192, 256, 0, stream>>>(x, xb, MTOT * DMODEL);
  cast_w4<<<4096, 256, 0, stream>>>(Wq, Wk, Wv, Wo, wqb);
  pack_mask<<<2048, 256, 0, stream>>>(mask, mbits);

  gemm_qkv<<<dim3(64, 24), 256, 0, stream>>>(xb, wqb, qb, kb, vT);

  attn_kernel<<<1024, 256, 0, stream>>>(qb, kb, vT, alibi, mbits, ob);

  gemm_out<<<dim3(64, 8), 256, 0, stream>>>(ob, wob, out);
}

// Round 19
// 355.018 us; speedup vs baseline: 2.4715x; 1.0012x over previous
//
#include <hip/hip_runtime.h>

#define NSEQ 2048
#define DMODEL 1024
#define NHEAD 16
#define HDIM 64
#define NBATCH 4
#define MTOT 8192
#define ATT_SCALE 0.125f
#define LOG2E 1.4426950408889634f
#define SM_SHIFT 12.0f

typedef __bf16 bf16x8 __attribute__((ext_vector_type(8)));
typedef float f32x4 __attribute__((ext_vector_type(4)));
typedef unsigned int u32x4 __attribute__((ext_vector_type(4)));
typedef unsigned short u16;
typedef unsigned int u32;
typedef unsigned long long u64;

__device__ __forceinline__ u16 f2bf(float f) {
  u32 u = __builtin_bit_cast(u32, f);
  return (u16)((u + 0x7fffu + ((u >> 16) & 1u)) >> 16);
}

__device__ __forceinline__ void gload_lds16(const void* g, void* l) {
  __builtin_amdgcn_global_load_lds(
      (__attribute__((address_space(1))) const u32*)g,
      (__attribute__((address_space(3))) u32*)l, 16, 0, 0);
}

// ---------------- cast fp32 -> bf16 (x) ----------------
__global__ __launch_bounds__(256) void cast_f32_bf16(const float* __restrict__ in,
                                                     u16* __restrict__ out, int n) {
  int i = (blockIdx.x * 256 + threadIdx.x) * 4;
  if (i >= n) return;
  float4 v = *(const float4*)(in + i);
  ushort4 o;
  o.x = f2bf(v.x); o.y = f2bf(v.y); o.z = f2bf(v.z); o.w = f2bf(v.w);
  *(ushort4*)(out + i) = o;
}

// ---------------- cast 4 weights -> contiguous bf16 block ----------------
__global__ __launch_bounds__(256) void cast_w4(const float* __restrict__ a,
                                               const float* __restrict__ b,
                                               const float* __restrict__ c,
                                               const float* __restrict__ d,
                                               u16* __restrict__ out) {
  int bid = blockIdx.x;
  int which = bid >> 10, lb = bid & 1023;
  const float* src = (which == 0) ? a : (which == 1) ? b : (which == 2) ? c : d;
  int i = (lb * 256 + threadIdx.x) * 4;
  float4 v = *(const float4*)(src + i);
  ushort4 o;
  o.x = f2bf(v.x); o.y = f2bf(v.y); o.z = f2bf(v.z); o.w = f2bf(v.w);
  *(ushort4*)(out + (size_t)which * 1048576 + i) = o;
}

// ---------------- pack mask int32 -> bit per element ----------------
__global__ __launch_bounds__(256) void pack_mask(const int* __restrict__ mask,
                                                 u64* __restrict__ bits) {
  int wave = (blockIdx.x * 256 + threadIdx.x) >> 6;
  int lane = threadIdx.x & 63;
  const int* row = mask + (size_t)wave * NSEQ;
  u64* out = bits + (size_t)wave * 32;
  for (int c = 0; c < 32; ++c) {
    int v = row[c * 64 + lane];
    u64 bl = __ballot(v != 0);
    if (lane == 0) out[c] = bl;
  }
}

// ---------------- fused QKV GEMM: C[m,n] = sum_k A[m,k]*Wc[n,k], N=3072 ----------------
// bn 0..7 -> Q [B,H,N,64]; 8..15 -> K [B,H,N,64]; 16..23 -> V^T [B,H,64,NSEQ]
__global__ __launch_bounds__(256) void gemm_qkv(const u16* __restrict__ A,
                                                const u16* __restrict__ Wc,
                                                u16* __restrict__ qo,
                                                u16* __restrict__ ko,
                                                u16* __restrict__ vo) {
  __shared__ __align__(16) u16 Al[128 * 64];
  __shared__ __align__(16) u16 Bl[128 * 64];
  const int tid = threadIdx.x;
  const int w = tid >> 6, l = tid & 63;
  const int l15 = l & 15, l4 = l >> 4;
  const int bm = blockIdx.x, bn = blockIdx.y;
  const int wm = w >> 1, wn = w & 1;

  f32x4 acc[4][4] = {};

  for (int ks = 0; ks < 1024; ks += 64) {
    __syncthreads();
#pragma unroll
    for (int c = 0; c < 4; ++c) {
      int g = w * 256 + c * 64 + l;
      int row = g >> 3, gc = g & 7;
      int sgc = gc ^ (row & 7);
      gload_lds16(A + (size_t)(bm * 128 + row) * 1024 + ks + sgc * 8, &Al[g * 8]);
      gload_lds16(Wc + (size_t)(bn * 128 + row) * 1024 + ks + sgc * 8, &Bl[g * 8]);
    }
    __syncthreads();
#pragma unroll
    for (int kc = 0; kc < 2; ++kc) {
      bf16x8 af[4], bfr[4];
#pragma unroll
      for (int mi = 0; mi < 4; ++mi) {
        int row = wm * 64 + mi * 16 + l15;
        int gc2 = (kc * 4 + l4) ^ (row & 7);
        af[mi] = *(const bf16x8*)&Al[row * 64 + gc2 * 8];
      }
#pragma unroll
      for (int ni = 0; ni < 4; ++ni) {
        int row = wn * 64 + ni * 16 + l15;
        int gc2 = (kc * 4 + l4) ^ (row & 7);
        bfr[ni] = *(const bf16x8*)&Bl[row * 64 + gc2 * 8];
      }
#pragma unroll
      for (int mi = 0; mi < 4; ++mi)
#pragma unroll
        for (int ni = 0; ni < 4; ++ni)
          acc[mi][ni] = __builtin_amdgcn_mfma_f32_16x16x32_bf16(af[mi], bfr[ni],
                                                                acc[mi][ni], 0, 0, 0);
    }
  }

  const int which = bn >> 3;
#pragma unroll
  for (int mi = 0; mi < 4; ++mi)
#pragma unroll
    for (int ni = 0; ni < 4; ++ni)
#pragma unroll
      for (int r = 0; r < 4; ++r) {
        int m = bm * 128 + wm * 64 + mi * 16 + l4 * 4 + r;
        int n = (bn & 7) * 128 + wn * 64 + ni * 16 + l15;
        int b = m >> 11, row = m & 2047, h = n >> 6, d = n & 63;
        u16 val = f2bf(acc[mi][ni][r]);
        size_t bh = (size_t)(b * 16 + h);
        if (which == 0)      qo[(bh * NSEQ + row) * 64 + d] = val;
        else if (which == 1) ko[(bh * NSEQ + row) * 64 + d] = val;
        else                 vo[(bh * 64 + d) * NSEQ + row] = val;
      }
}

// ---------------- final GEMM: out[m,n] = sum_k A[m,k]*W[n,k], fp32 out ----------------
__global__ __launch_bounds__(256) void gemm_out(const u16* __restrict__ A,
                                                const u16* __restrict__ W,
                                                float* __restrict__ C) {
  __shared__ __align__(16) u16 Al[128 * 64];
  __shared__ __align__(16) u16 Bl[128 * 64];
  const int tid = threadIdx.x;
  const int w = tid >> 6, l = tid & 63;
  const int l15 = l & 15, l4 = l >> 4;
  const int bm = blockIdx.x, bn = blockIdx.y;
  const int wm = w >> 1, wn = w & 1;

  f32x4 acc[4][4] = {};

  for (int ks = 0; ks < 1024; ks += 64) {
    __syncthreads();
#pragma unroll
    for (int c = 0; c < 4; ++c) {
      int g = w * 256 + c * 64 + l;
      int row = g >> 3, gc = g & 7;
      int sgc = gc ^ (row & 7);
      gload_lds16(A + (size_t)(bm * 128 + row) * 1024 + ks + sgc * 8, &Al[g * 8]);
      gload_lds16(W + (size_t)(bn * 128 + row) * 1024 + ks + sgc * 8, &Bl[g * 8]);
    }
    __syncthreads();
#pragma unroll
    for (int kc = 0; kc < 2; ++kc) {
      bf16x8 af[4], bfr[4];
#pragma unroll
      for (int mi = 0; mi < 4; ++mi) {
        int row = wm * 64 + mi * 16 + l15;
        int gc2 = (kc * 4 + l4) ^ (row & 7);
        af[mi] = *(const bf16x8*)&Al[row * 64 + gc2 * 8];
      }
#pragma unroll
      for (int ni = 0; ni < 4; ++ni) {
        int row = wn * 64 + ni * 16 + l15;
        int gc2 = (kc * 4 + l4) ^ (row & 7);
        bfr[ni] = *(const bf16x8*)&Bl[row * 64 + gc2 * 8];
      }
#pragma unroll
      for (int mi = 0; mi < 4; ++mi)
#pragma unroll
        for (int ni = 0; ni < 4; ++ni)
          acc[mi][ni] = __builtin_amdgcn_mfma_f32_16x16x32_bf16(af[mi], bfr[ni],
                                                                acc[mi][ni], 0, 0, 0);
    }
  }

#pragma unroll
  for (int mi = 0; mi < 4; ++mi)
#pragma unroll
    for (int ni = 0; ni < 4; ++ni)
#pragma unroll
      for (int r = 0; r < 4; ++r) {
        int m = bm * 128 + wm * 64 + mi * 16 + l4 * 4 + r;
        int n = bn * 128 + wn * 64 + ni * 16 + l15;
        C[(size_t)m * 1024 + n] = acc[mi][ni][r];
      }
}

// ---------------- flash attention (r17 verified best: 240 us attn / 355 us total) ----------------
// 256 thr = 4 waves, grid 1024; each wave handles TWO 16-row q-groups ->
// 36 MFMA per stage+barrier, 2x K/V reuse. __launch_bounds__(256,2) gives the
// allocator room (VGPR 100, no spill). Each GROUP loads its own alibi/mask
// just-in-time and reads K/V fragments from LDS right before each MFMA
// (hoisting either one spills or NaNs -- r15/r16/r18 dead lines). Fixed-shift
// softmax + ones-trick row-sum; K staged row-permuted; V contiguous b128;
// batch-innermost XCD decode.
__global__ __launch_bounds__(256, 2) void attn_kernel(
    const u16* __restrict__ q, const u16* __restrict__ k, const u16* __restrict__ vT,
    const float* __restrict__ alibi, const u64* __restrict__ mbits,
    u16* __restrict__ o) {
  __shared__ __align__(16) u16 Kl[2][64 * 64];
  __shared__ __align__(16) u16 Vl[2][64 * 64];

  const int tid = threadIdx.x, w = tid >> 6, l = tid & 63;
  const int l15 = l & 15, l4 = l >> 4;
  const int W = blockIdx.x;
  // 1024 = 8 XCD * 128; batch innermost for alibi L2 reuse
  const int W2 = (W & 7) * 128 + (W >> 3);
  const int b = W2 & 3, hq = W2 >> 2;
  const int qb = hq & 15, h = hq >> 4;
  const int bh = b * 16 + h;
  const int wq0 = qb * 128 + w * 16;      // group0 rows [wq0, wq0+16)
  const int myq0 = wq0 + l15;             // group1 rows [wq0+64, wq0+80)
  const int myq1 = wq0 + 64 + l15;

  // Q fragments for both groups (B-operand: col q = l15)
  bf16x8 aq0, aq1, aq2, aq3;
  {
    const u16* qrow0 = q + ((size_t)bh * NSEQ + myq0) * 64;
    aq0 = *(const bf16x8*)(qrow0 + l4 * 8);
    aq1 = *(const bf16x8*)(qrow0 + 32 + l4 * 8);
    const u16* qrow1 = q + ((size_t)bh * NSEQ + myq1) * 64;
    aq2 = *(const bf16x8*)(qrow1 + l4 * 8);
    aq3 = *(const bf16x8*)(qrow1 + 32 + l4 * 8);
  }

  // staging pointers. K rows permuted: LDS row p holds global row
  // 32*(p>>5) + 8*((p>>2)&3) + 4*((p>>4)&1) + (p&3)
  const u16* kg[2]; const u16* vg[2];
#pragma unroll
  for (int c = 0; c < 2; ++c) {
    int g = w * 128 + c * 64 + l;
    int row = g >> 3, gc = g & 7, sgc = gc ^ (row & 7);
    int srow = (row & 0x23) | (((row >> 2) & 3) << 3) | (((row >> 4) & 1) << 2);
    kg[c] = k + ((size_t)bh * NSEQ + srow) * 64 + sgc * 8;
    vg[c] = vT + ((size_t)bh * 64 + row) * NSEQ + sgc * 8;
  }

  // per-lane alibi / mask pointers for both q-groups
  const float* alp0 = alibi + (size_t)h * NSEQ * NSEQ + (size_t)myq0 * NSEQ + 8 * l4;
  const float* alp1 = alibi + (size_t)h * NSEQ * NSEQ + (size_t)myq1 * NSEQ + 8 * l4;
  const u64* mrp0 = mbits + ((size_t)b * NSEQ + myq0) * 32;
  const u64* mrp1 = mbits + ((size_t)b * NSEQ + myq1) * 32;

  // LDS read offsets (K and V identical pattern, conflict-free b128)
  const int kfr0 = l15 * 128 + (((0 + l4) ^ (l15 & 7)) << 4);
  const int kfr1 = l15 * 128 + (((4 + l4) ^ (l15 & 7)) << 4);

  const u32x4 onesu = {0x3F803F80u, 0x3F803F80u, 0x3F803F80u, 0x3F803F80u};
  const bf16x8 bones = __builtin_bit_cast(bf16x8, onesu);

  f32x4 oaccA[4] = {};  // group0: q = wq0 + l4*4 + r, d = db*16 + l15
  f32x4 oaccB[4] = {};  // group1: q = wq0 + 64 + l4*4 + r
  f32x4 osumA = {}, osumB = {};

  auto stage = [&](u16* KB, u16* VB) {
#pragma unroll
    for (int c = 0; c < 2; ++c) {
      gload_lds16(kg[c], (char*)KB + (w * 128 + c * 64 + l) * 16);
      kg[c] += 4096;
      gload_lds16(vg[c], (char*)VB + (w * 128 + c * 64 + l) * 16);
      vg[c] += 64;
    }
  };

  stage(Kl[0], Vl[0]);
  __syncthreads();

  // One q-group: loads its own alibi/mask, reads K/V from LDS just-in-time.
  // (kb,r) -> global k = 32*(kb>>1) + 8*l4 + 4*(kb&1) + r (K-row permutation)
#define GROUP(KB, VB, AQ0, AQ1, ALP, MRP, OSUM, OACC, t)                       \
  {                                                                            \
    float4 A0 = *(const float4*)((ALP) + (t) * 64);                            \
    float4 A1 = *(const float4*)((ALP) + (t) * 64 + 4);                        \
    float4 A2 = *(const float4*)((ALP) + (t) * 64 + 32);                       \
    float4 A3 = *(const float4*)((ALP) + (t) * 64 + 36);                       \
    u64 mb = (MRP)[t];                                                         \
    f32x4 st[4];                                                               \
    _Pragma("unroll")                                                          \
    for (int kb = 0; kb < 4; ++kb) {                                           \
      f32x4 z = {0.f, 0.f, 0.f, 0.f};                                          \
      st[kb] = z;                                                              \
      bf16x8 bk = *(const bf16x8*)((const char*)(KB) + kfr0 + kb * 2048);      \
      st[kb] = __builtin_amdgcn_mfma_f32_16x16x32_bf16(bk, AQ0, st[kb], 0, 0, 0); \
      bk = *(const bf16x8*)((const char*)(KB) + kfr1 + kb * 2048);             \
      st[kb] = __builtin_amdgcn_mfma_f32_16x16x32_bf16(bk, AQ1, st[kb], 0, 0, 0); \
    }                                                                          \
    st[0][0] = fmaf(st[0][0], ATT_SCALE, A0.x);                                \
    st[0][1] = fmaf(st[0][1], ATT_SCALE, A0.y);                                \
    st[0][2] = fmaf(st[0][2], ATT_SCALE, A0.z);                                \
    st[0][3] = fmaf(st[0][3], ATT_SCALE, A0.w);                                \
    st[1][0] = fmaf(st[1][0], ATT_SCALE, A1.x);                                \
    st[1][1] = fmaf(st[1][1], ATT_SCALE, A1.y);                                \
    st[1][2] = fmaf(st[1][2], ATT_SCALE, A1.z);                                \
    st[1][3] = fmaf(st[1][3], ATT_SCALE, A1.w);                                \
    st[2][0] = fmaf(st[2][0], ATT_SCALE, A2.x);                                \
    st[2][1] = fmaf(st[2][1], ATT_SCALE, A2.y);                                \
    st[2][2] = fmaf(st[2][2], ATT_SCALE, A2.z);                                \
    st[2][3] = fmaf(st[2][3], ATT_SCALE, A2.w);                                \
    st[3][0] = fmaf(st[3][0], ATT_SCALE, A3.x);                                \
    st[3][1] = fmaf(st[3][1], ATT_SCALE, A3.y);                                \
    st[3][2] = fmaf(st[3][2], ATT_SCALE, A3.z);                                \
    st[3][3] = fmaf(st[3][3], ATT_SCALE, A3.w);                                \
    if (!__all(mb == ~0ull)) {                                                 \
      _Pragma("unroll")                                                        \
      for (int r = 0; r < 4; ++r) {                                            \
        if (!((mb >> (8 * l4 + r)) & 1))      st[0][r] = -3.0e38f;             \
        if (!((mb >> (8 * l4 + 4 + r)) & 1))  st[1][r] = -3.0e38f;             \
        if (!((mb >> (32 + 8 * l4 + r)) & 1)) st[2][r] = -3.0e38f;             \
        if (!((mb >> (36 + 8 * l4 + r)) & 1)) st[3][r] = -3.0e38f;             \
      }                                                                        \
    }                                                                          \
    float p[16];                                                               \
    _Pragma("unroll")                                                          \
    for (int kb = 0; kb < 4; ++kb)                                             \
      _Pragma("unroll")                                                        \
      for (int r = 0; r < 4; ++r)                                              \
        p[kb * 4 + r] = exp2f(fmaf(st[kb][r], LOG2E, -SM_SHIFT * LOG2E));      \
    u32 Wp[8];                                                                 \
    _Pragma("unroll")                                                          \
    for (int i = 0; i < 8; ++i)                                                \
      asm("v_cvt_pk_bf16_f32 %0, %1, %2" : "=v"(Wp[i]) : "v"(p[2 * i]), "v"(p[2 * i + 1])); \
    {                                                                          \
      u32x4 wv0 = {Wp[0], Wp[1], Wp[2], Wp[3]};                                \
      bf16x8 pa = __builtin_bit_cast(bf16x8, wv0);                             \
      OSUM = __builtin_amdgcn_mfma_f32_16x16x32_bf16(pa, bones, OSUM, 0, 0, 0);\
      _Pragma("unroll")                                                        \
      for (int db = 0; db < 4; ++db) {                                         \
        bf16x8 bv = *(const bf16x8*)((const char*)(VB) + kfr0 + db * 2048);    \
        OACC[db] = __builtin_amdgcn_mfma_f32_16x16x32_bf16(pa, bv, OACC[db], 0, 0, 0); \
      }                                                                        \
      u32x4 wv1 = {Wp[4], Wp[5], Wp[6], Wp[7]};                                \
      pa = __builtin_bit_cast(bf16x8, wv1);                                    \
      OSUM = __builtin_amdgcn_mfma_f32_16x16x32_bf16(pa, bones, OSUM, 0, 0, 0);\
      _Pragma("unroll")                                                        \
      for (int db = 0; db < 4; ++db) {                                         \
        bf16x8 bv = *(const bf16x8*)((const char*)(VB) + kfr1 + db * 2048);    \
        OACC[db] = __builtin_amdgcn_mfma_f32_16x16x32_bf16(pa, bv, OACC[db], 0, 0, 0); \
      }                                                                        \
    }                                                                          \
  }

  auto body = [&](const u16* KB, const u16* VB, u16* KN, u16* VN, int t, bool dost) {
    if (dost) stage(KN, VN);
    GROUP(KB, VB, aq0, aq1, alp0, mrp0, osumA, oaccA, t)
    GROUP(KB, VB, aq2, aq3, alp1, mrp1, osumB, oaccB, t)
    __syncthreads();
  };

  for (int t2 = 0; t2 < 16; ++t2) {
    body(Kl[0], Vl[0], Kl[1], Vl[1], t2 * 2, true);
    body(Kl[1], Vl[1], Kl[0], Vl[0], t2 * 2 + 1, t2 < 15);
  }
#undef GROUP

  // normalize + write O for both groups; shfl-free
#pragma unroll
  for (int r = 0; r < 4; ++r) {
    float invA = __builtin_amdgcn_rcpf(osumA[r]);
    int qq = wq0 + l4 * 4 + r;
    u16* orow = o + ((size_t)b * NSEQ + qq) * DMODEL + h * 64 + l15;
    orow[0]  = f2bf(oaccA[0][r] * invA);
    orow[16] = f2bf(oaccA[1][r] * invA);
    orow[32] = f2bf(oaccA[2][r] * invA);
    orow[48] = f2bf(oaccA[3][r] * invA);
    float invB = __builtin_amdgcn_rcpf(osumB[r]);
    u16* orow2 = o + ((size_t)b * NSEQ + qq + 64) * DMODEL + h * 64 + l15;
    orow2[0]  = f2bf(oaccB[0][r] * invB);
    orow2[16] = f2bf(oaccB[1][r] * invB);
    orow2[32] = f2bf(oaccB[2][r] * invB);
    orow2[48] = f2bf(oaccB[3][r] * invB);
  }
}

extern "C" void kernel_launch(void* const* d_in, const int* in_sizes, int n_in,
                              void* d_out, int out_size, void* d_ws, size_t ws_size,
                              hipStream_t stream) {
  (void)in_sizes; (void)n_in; (void)out_size; (void)ws_size;
  const float* x = (const float*)d_in[0];
  const int* mask = (const int*)d_in[1];
  const float* alibi = (const float*)d_in[2];
  const float* Wq = (const float*)d_in[3];
  const float* Wk = (const float*)d_in[4];
  const float* Wv = (const float*)d_in[5];
  const float* Wo = (const float*)d_in[6];
  float* out = (float*)d_out;

  char* ws = (char*)d_ws;
  const size_t MB = 1u << 20;
  u16* xb  = (u16*)(ws + 0 * MB);    // 16 MB
  u16* wqb = (u16*)(ws + 16 * MB);   // 8 MB (wq,wk,wv,wo contiguous)
  u16* wob = (u16*)(ws + 22 * MB);
  u16* qb  = (u16*)(ws + 24 * MB);   // 16 MB  [B,H,N,64]
  u16* kb  = (u16*)(ws + 40 * MB);   // 16 MB  [B,H,N,64]
  u16* vT  = (u16*)(ws + 56 * MB);   // 16 MB  [B,H,64,N]
  u16* ob  = (u16*)(ws + 72 * MB);   // 16 MB  [B,N,1024]
  u64* mbits = (u64*)(ws + 88 * MB); // 2 MB   [B*N][32]

  cast_f32_bf16<<<8192, 256, 0, stream>>>(x, xb, MTOT * DMODEL);
  cast_w4<<<4096, 256, 0, stream>>>(Wq, Wk, Wv, Wo, wqb);
  pack_mask<<<2048, 256, 0, stream>>>(mask, mbits);

  gemm_qkv<<<dim3(64, 24), 256, 0, stream>>>(xb, wqb, qb, kb, vT);

  attn_kernel<<<2048 / 2, 256, 0, stream>>>(qb, kb, vT, alibi, mbits, ob);

  gemm_out<<<dim3(64, 8), 256, 0, stream>>>(ob, wob, out);
}